// Round 10
// baseline (209.628 us; speedup 1.0000x reference)
//
#include <hip/hip_runtime.h>

#define T_DATA 20000
#define S_NO   128
#define T_HIST 100
#define J_PAD  104              // conv taps padded to 13 chunks of 8 (zeros past 99)
#define NELEM  (T_DATA * S_NO)  // 2,560,000

__device__ __forceinline__ float sigm(float v) {
    return 1.0f / (1.0f + __expf(-v));
}

__device__ __forceinline__ void fma4(float4& a, float s, const float4 c) {
    a.x = fmaf(s, c.x, a.x); a.y = fmaf(s, c.y, a.y);
    a.z = fmaf(s, c.z, a.z); a.w = fmaf(s, c.w, a.w);
}

__device__ __forceinline__ void fma2(float2& a, const float2 k, const float2 w) {
    a.x = fmaf(k.x, w.x, a.x); a.y = fmaf(k.y, w.y, a.y);
}

// ---------------------------------------------------------------------------
// K1: prep (17 blocks). blocks 0..15: transpose C -> Ct[k][s]
// block 16: ancestor kernel transposed [j][s] (padded to 104), history
// kernel [s][j], flag = any(K_hist != 0)
// ---------------------------------------------------------------------------
__global__ void __launch_bounds__(256) k1_prep(const float* __restrict__ C,
                        const float* __restrict__ K_spike,
                        const float* __restrict__ tau_spike,
                        const float* __restrict__ delta_spike,
                        const float* __restrict__ tau_hist,
                        const float* __restrict__ K_hist,
                        const float* __restrict__ delta_hist,
                        float* __restrict__ Ct,
                        float* __restrict__ anc_kT,
                        float* __restrict__ hist_k,
                        int* __restrict__ flag) {
    const int tid = threadIdx.x;
    const int b   = blockIdx.x;
    if (b < 16) {
#pragma unroll
        for (int i = 0; i < 4; ++i) {
            const int q = b * 1024 + i * 256 + tid;   // q = s*128 + k
            Ct[(q & 127) * S_NO + (q >> 7)] = C[q];
        }
        return;
    }
    const int s    = tid & 127;
    const int half = tid >> 7;
    {   // ancestor kernel transposed, padded: anc_kT[j*128 + s], j in [0,104)
        float d  = delta_spike[s];
        float i0 = __expf(-tau_spike[0]);
        float i1 = __expf(-tau_spike[1]);
        float i2 = __expf(-tau_spike[2]);
        float k0 = K_spike[s * 3 + 0], k1 = K_spike[s * 3 + 1], k2 = K_spike[s * 3 + 2];
        for (int j = half * 52; j < half * 52 + 52; ++j) {
            float v = 0.0f;
            if (j < T_HIST) {
                float t  = fmaxf((float)j - d, 0.0f);
                float x0 = t * i0, x1 = t * i1, x2 = t * i2;
                v = k0 * x0 * __expf(-x0) + k1 * x1 * __expf(-x1) + k2 * x2 * __expf(-x2);
            }
            anc_kT[j * S_NO + s] = v;
        }
    }
    {   // history kernel per-subunit: hist_k[s*100 + j]
        float d  = delta_hist[s];
        float i0 = __expf(-tau_hist[0]);
        float i1 = __expf(-tau_hist[1]);
        float i2 = __expf(-tau_hist[2]);
        float k0 = K_hist[s * 3 + 0], k1 = K_hist[s * 3 + 1], k2 = K_hist[s * 3 + 2];
        for (int j = half * 50; j < half * 50 + 50; ++j) {
            float t  = fmaxf((float)j - d, 0.0f);
            float x0 = t * i0, x1 = t * i1, x2 = t * i2;
            hist_k[s * T_HIST + j] =
                k0 * x0 * __expf(-x0) + k1 * x1 * __expf(-x1) + k2 * x2 * __expf(-x2);
        }
    }
    if (tid == 0) *flag = 0;
    __syncthreads();
    if (tid < 128) {
        if (K_hist[s * 3] != 0.0f || K_hist[s * 3 + 1] != 0.0f || K_hist[s * 3 + 2] != 0.0f)
            atomicOr(flag, 1);
    }
}

// ---------------------------------------------------------------------------
// K2 (production): dual GEMM, 1250 blocks x 16t, thread 2t x 4s, LDS-staged.
// MEASURED BEST (R8/R9 algebra: ~20 µs vs 28 for 32t, 48 for LDS-free).
// ---------------------------------------------------------------------------
__global__ void __launch_bounds__(256) k2_gemm16(const float* __restrict__ Z,
                                                 const float* __restrict__ Y,
                                                 const float* __restrict__ Ct,
                                                 float* __restrict__ A,
                                                 float* __restrict__ R) {
    __shared__ float Zt[16 * 128];
    __shared__ float Yt[16 * 128];
    const int t0  = blockIdx.x * 16;
    const int tid = threadIdx.x;
    {
        const float4* Zg = (const float4*)(Z + t0 * S_NO);
        const float4* Yg = (const float4*)(Y + t0 * S_NO);
        float4* Zl = (float4*)Zt;
        float4* Yl = (float4*)Yt;
        for (int q = tid; q < 512; q += 256) { Zl[q] = Zg[q]; Yl[q] = Yg[q]; }
    }
    __syncthreads();
    const int sg = tid & 31;          // s0 = sg*4
    const int tg = tid >> 5;          // 0..7 -> local t = tg*2 + i
    const int s0 = sg * 4;
    float4 accA[2] = {{0,0,0,0},{0,0,0,0}};
    float4 accR[2] = {{0,0,0,0},{0,0,0,0}};
    for (int k4 = 0; k4 < 32; ++k4) {
        const float4 c0 = *(const float4*)&Ct[(k4 * 4 + 0) * S_NO + s0];
        const float4 c1 = *(const float4*)&Ct[(k4 * 4 + 1) * S_NO + s0];
        const float4 c2 = *(const float4*)&Ct[(k4 * 4 + 2) * S_NO + s0];
        const float4 c3 = *(const float4*)&Ct[(k4 * 4 + 3) * S_NO + s0];
#pragma unroll
        for (int i = 0; i < 2; ++i) {
            const float4 z = *(const float4*)&Zt[(tg * 2 + i) * S_NO + k4 * 4];
            fma4(accA[i], z.x, c0); fma4(accA[i], z.y, c1);
            fma4(accA[i], z.z, c2); fma4(accA[i], z.w, c3);
            const float4 y = *(const float4*)&Yt[(tg * 2 + i) * S_NO + k4 * 4];
            fma4(accR[i], y.x, c0); fma4(accR[i], y.y, c1);
            fma4(accR[i], y.z, c2); fma4(accR[i], y.w, c3);
        }
    }
#pragma unroll
    for (int i = 0; i < 2; ++i) {
        *(float4*)&A[(t0 + tg * 2 + i) * S_NO + s0] = accA[i];
        *(float4*)&R[(t0 + tg * 2 + i) * S_NO + s0] = accR[i];
    }
}

// ---------------------------------------------------------------------------
// K3: fused 100-tap conv + final map. Thread: 2t x 2s (float2), so the grid
// carries 10000 waves = 9.8/SIMD (2x R7) to hide latency. Double-buffered
// chunk pipeline; all three cold streams (S_conv, noise, R) prefetched;
// bijective XCD swizzle over 2504 = 8*313 physical blocks.
// Block = 8t x 128s slab; 2500 logical blocks.
// ---------------------------------------------------------------------------
#define K3_LOGICAL 2500
#define K3_NPER    313                 // ceil(2500/8)
#define K3_PHYS    (8 * K3_NPER)       // 2504

__device__ __forceinline__ void k3_load_chunk2(const float* __restrict__ A,
                                               const float* __restrict__ kT,
                                               int t0, int s0, int c,
                                               float2 w[9], float2 kj[8]) {
    const int B = t0 - 8 * c - 8;
#pragma unroll
    for (int q = 0; q < 9; ++q) w[q] = *(const float2*)&A[(B + q) * S_NO + s0];
#pragma unroll
    for (int r = 0; r < 8; ++r) kj[r] = *(const float2*)&kT[(8 * c + r) * S_NO + s0];
}

__device__ __forceinline__ void k3_fma_chunk2(const float2 w[9], const float2 kj[8],
                                              float2 acc[2]) {
#pragma unroll
    for (int r = 0; r < 8; ++r)
#pragma unroll
        for (int i = 0; i < 2; ++i)
            fma2(acc[i], kj[r], w[i + 7 - r]);   // row = t0+i-1-(8c+r) = B + (i+7-r)
}

__device__ __forceinline__ void conv2_guard(const float* __restrict__ A,
                                            const float* __restrict__ kT,
                                            int t0, int s0, float2 acc[2]) {
#pragma unroll 1
    for (int c = 0; c < 13; ++c) {
        const int B = t0 - 8 * c - 8;
        float2 w[9], kj[8];
#pragma unroll
        for (int q = 0; q < 9; ++q) {
            const int u = B + q;
            w[q] = (u >= 0) ? *(const float2*)&A[u * S_NO + s0] : make_float2(0.f, 0.f);
        }
#pragma unroll
        for (int r = 0; r < 8; ++r) kj[r] = *(const float2*)&kT[(8 * c + r) * S_NO + s0];
        k3_fma_chunk2(w, kj, acc);
    }
}

__global__ void __launch_bounds__(256, 4) k3_fused(const float* __restrict__ A,
                                                const float* __restrict__ anc_kT,
                                                const float* __restrict__ S_conv,
                                                const float* __restrict__ noise,
                                                const float* __restrict__ W_sub,
                                                const float* __restrict__ theta_syn,
                                                const float* __restrict__ theta_spike,
                                                const float* __restrict__ W_spike,
                                                const int* __restrict__ flag,
                                                float* __restrict__ out0,
                                                float* __restrict__ out1,
                                                float* __restrict__ out2,
                                                float* __restrict__ out3,
                                                float* __restrict__ Fws) {
    const int blk = (blockIdx.x & 7) * K3_NPER + (blockIdx.x >> 3);
    if (blk >= K3_LOGICAL) return;
    const int tid = threadIdx.x;
    const int s0  = (tid & 63) * 2;
    const int tg  = tid >> 6;                             // wave-uniform (0..3)
    const int t0  = blk * 8 + tg * 2;
    const int fl  = *flag;

    // prefetch all cold streams; latency hides under the conv
    float2 sc[2], nz[2], rr[2];
#pragma unroll
    for (int i = 0; i < 2; ++i) {
        const int n = (t0 + i) * S_NO + s0;
        sc[i] = *(const float2*)&S_conv[n];
        nz[i] = *(const float2*)&noise[n];
        rr[i] = *(const float2*)&out1[n];
    }

    float2 acc[2] = {{0.f, 0.f}, {0.f, 0.f}};
    if (t0 >= J_PAD) {
        float2 w0[9], k0[8], w1[9], k1[8];
        k3_load_chunk2(A, anc_kT, t0, s0, 0, w0, k0);
#pragma unroll 1
        for (int c = 0; c < 12; c += 2) {
            k3_load_chunk2(A, anc_kT, t0, s0, c + 1, w1, k1);
            k3_fma_chunk2(w0, k0, acc);
            k3_load_chunk2(A, anc_kT, t0, s0, c + 2, w0, k0);
            k3_fma_chunk2(w1, k1, acc);
        }
        k3_fma_chunk2(w0, k0, acc);                       // chunk 12
    } else {
        conv2_guard(A, anc_kT, t0, s0, acc);
    }

    if (fl == 0) {
        const float2 tsy = *(const float2*)&theta_syn[s0];
        const float2 wsb = *(const float2*)&W_sub[s0];
        const float2 wsp = *(const float2*)&W_spike[s0];
        const float2 tsp = *(const float2*)&theta_spike[s0];
#pragma unroll
        for (int i = 0; i < 2; ++i) {
            const int n = (t0 + i) * S_NO + s0;
            float2 y, z, dn;
            {
                const float x = sigm(sc[i].x + tsy.x + rr[i].x + acc[i].x);
                y.x = x * wsb.x; dn.x = fmaf(x, wsp.x, tsp.x); z.x = sigm(dn.x + nz[i].x);
            }
            {
                const float x = sigm(sc[i].y + tsy.y + rr[i].y + acc[i].y);
                y.y = x * wsb.y; dn.y = fmaf(x, wsp.y, tsp.y); z.y = sigm(dn.y + nz[i].y);
            }
            *(float2*)&out0[n] = y;
            *(float2*)&out1[n] = z;
            *(float2*)&out2[n] = dn;
            *(float2*)&out3[n] = dn;
        }
    } else {
#pragma unroll
        for (int i = 0; i < 2; ++i)
            *(float2*)&Fws[(t0 + i) * S_NO + s0] = acc[i];
    }
}

// ---------------------------------------------------------------------------
// K4: exact sequential recurrence (only when hist kernel != 0).
// ---------------------------------------------------------------------------
__global__ void __launch_bounds__(64) k4_scan(const float* __restrict__ S_conv,
                                              const float* __restrict__ noise,
                                              const float* __restrict__ W_sub,
                                              const float* __restrict__ theta_syn,
                                              const float* __restrict__ theta_spike,
                                              const float* __restrict__ W_spike,
                                              const float* __restrict__ hist_k,
                                              const int* __restrict__ flag,
                                              const float* __restrict__ Fws,
                                              float* __restrict__ out0,
                                              float* __restrict__ out1,
                                              float* __restrict__ out2,
                                              float* __restrict__ out3) {
    if (*flag == 0) return;
    __shared__ float zr[128];
    const int s = blockIdx.x;
    const int l = threadIdx.x;
    zr[l] = 0.0f; zr[l + 64] = 0.0f;
    const float hk0 = (l < T_HIST) ? hist_k[s * T_HIST + l] : 0.0f;
    const float hk1 = (l + 64 < T_HIST) ? hist_k[s * T_HIST + l + 64] : 0.0f;
    const float tsy = theta_syn[s], wsub = W_sub[s];
    const float wsp = W_spike[s],  tsp  = theta_spike[s];
    for (int t = 0; t < T_DATA; ++t) {
        float fh = hk0 * zr[(t - 1 - l) & 127];
        fh = fmaf(hk1, zr[(t - 65 - l) & 127], fh);
#pragma unroll
        for (int m = 1; m < 64; m <<= 1) fh += __shfl_xor(fh, m, 64);
        const int n = t * S_NO + s;
        const float basev = S_conv[n] + tsy + out1[n] + Fws[n];
        const float x  = sigm(basev + fh);
        const float dn = fmaf(x, wsp, tsp);
        const float z  = sigm(dn + noise[n]);
        if (l == 0) {
            out0[n] = x * wsub;
            out1[n] = z;
            out2[n] = dn;
            out3[n] = dn;
            zr[t & 127] = z;
        }
    }
}

// ---------------------------------------------------------------------------
extern "C" void kernel_launch(void* const* d_in, const int* in_sizes, int n_in,
                              void* d_out, int out_size, void* d_ws, size_t ws_size,
                              hipStream_t stream) {
    const float* S_conv  = (const float*)d_in[0];
    const float* Y_anc   = (const float*)d_in[1];
    const float* Z_anc   = (const float*)d_in[2];
    const float* noise   = (const float*)d_in[3];
    const float* C_den   = (const float*)d_in[4];
    const float* W_sub   = (const float*)d_in[5];
    const float* th_syn  = (const float*)d_in[6];
    const float* K_spk   = (const float*)d_in[7];
    const float* tau_spk = (const float*)d_in[8];
    const float* dl_spk  = (const float*)d_in[9];
    const float* th_spk  = (const float*)d_in[10];
    const float* W_spk   = (const float*)d_in[11];
    const float* tau_h   = (const float*)d_in[12];
    const float* K_h     = (const float*)d_in[13];
    const float* dl_h    = (const float*)d_in[14];

    float* out  = (float*)d_out;
    float* out0 = out;
    float* out1 = out + NELEM;
    float* out2 = out + 2 * NELEM;
    float* out3 = out + 3 * NELEM;

    // workspace: A | F | Ct | anc_kT (104 rows) | hist_k | flag
    float* ws     = (float*)d_ws;
    float* wsA    = ws;
    float* wsF    = ws + NELEM;
    float* Ct     = ws + 2 * NELEM;
    float* anc_kT = Ct + S_NO * S_NO;
    float* hist_k = anc_kT + J_PAD * S_NO;
    int*   flag   = (int*)(hist_k + S_NO * T_HIST);

    k1_prep<<<17, 256, 0, stream>>>(C_den, K_spk, tau_spk, dl_spk, tau_h, K_h, dl_h,
                                    Ct, anc_kT, hist_k, flag);
    // A -> ws, R -> out1
    k2_gemm16<<<T_DATA / 16, 256, 0, stream>>>(Z_anc, Y_anc, Ct, wsA, out1);
    // fused conv + final map (reads A from ws, R from out1)
    k3_fused<<<K3_PHYS, 256, 0, stream>>>(wsA, anc_kT, S_conv, noise,
                                          W_sub, th_syn, th_spk, W_spk,
                                          flag, out0, out1, out2, out3, wsF);
    // exact sequential path (no-op when hist kernel is all-zero)
    k4_scan<<<S_NO, 64, 0, stream>>>(S_conv, noise, W_sub, th_syn, th_spk, W_spk,
                                     hist_k, flag, wsF, out0, out1, out2, out3);
}

// Round 11
// 165.092 us; speedup vs baseline: 1.2698x; 1.2698x over previous
//
#include <hip/hip_runtime.h>

#define T_DATA 20000
#define S_NO   128
#define T_HIST 100
#define J_PAD  104              // conv taps padded to 13 chunks of 8 (zeros past 99)
#define NELEM  (T_DATA * S_NO)  // 2,560,000

__device__ __forceinline__ float sigm(float v) {
    return 1.0f / (1.0f + __expf(-v));
}

__device__ __forceinline__ void fma4(float4& a, float s, const float4 c) {
    a.x = fmaf(s, c.x, a.x); a.y = fmaf(s, c.y, a.y);
    a.z = fmaf(s, c.z, a.z); a.w = fmaf(s, c.w, a.w);
}

// ---------------------------------------------------------------------------
// K1: prep (17 blocks). blocks 0..15: transpose C -> Ct[k][s]
// block 16: ancestor kernel transposed [j][s] (padded to 104), history
// kernel [s][j], flag = any(K_hist != 0)
// ---------------------------------------------------------------------------
__global__ void __launch_bounds__(256) k1_prep(const float* __restrict__ C,
                        const float* __restrict__ K_spike,
                        const float* __restrict__ tau_spike,
                        const float* __restrict__ delta_spike,
                        const float* __restrict__ tau_hist,
                        const float* __restrict__ K_hist,
                        const float* __restrict__ delta_hist,
                        float* __restrict__ Ct,
                        float* __restrict__ anc_kT,
                        float* __restrict__ hist_k,
                        int* __restrict__ flag) {
    const int tid = threadIdx.x;
    const int b   = blockIdx.x;
    if (b < 16) {
#pragma unroll
        for (int i = 0; i < 4; ++i) {
            const int q = b * 1024 + i * 256 + tid;   // q = s*128 + k
            Ct[(q & 127) * S_NO + (q >> 7)] = C[q];
        }
        return;
    }
    const int s    = tid & 127;
    const int half = tid >> 7;
    {   // ancestor kernel transposed, padded: anc_kT[j*128 + s], j in [0,104)
        float d  = delta_spike[s];
        float i0 = __expf(-tau_spike[0]);
        float i1 = __expf(-tau_spike[1]);
        float i2 = __expf(-tau_spike[2]);
        float k0 = K_spike[s * 3 + 0], k1 = K_spike[s * 3 + 1], k2 = K_spike[s * 3 + 2];
        for (int j = half * 52; j < half * 52 + 52; ++j) {
            float v = 0.0f;
            if (j < T_HIST) {
                float t  = fmaxf((float)j - d, 0.0f);
                float x0 = t * i0, x1 = t * i1, x2 = t * i2;
                v = k0 * x0 * __expf(-x0) + k1 * x1 * __expf(-x1) + k2 * x2 * __expf(-x2);
            }
            anc_kT[j * S_NO + s] = v;
        }
    }
    {   // history kernel per-subunit: hist_k[s*100 + j]
        float d  = delta_hist[s];
        float i0 = __expf(-tau_hist[0]);
        float i1 = __expf(-tau_hist[1]);
        float i2 = __expf(-tau_hist[2]);
        float k0 = K_hist[s * 3 + 0], k1 = K_hist[s * 3 + 1], k2 = K_hist[s * 3 + 2];
        for (int j = half * 50; j < half * 50 + 50; ++j) {
            float t  = fmaxf((float)j - d, 0.0f);
            float x0 = t * i0, x1 = t * i1, x2 = t * i2;
            hist_k[s * T_HIST + j] =
                k0 * x0 * __expf(-x0) + k1 * x1 * __expf(-x1) + k2 * x2 * __expf(-x2);
        }
    }
    if (tid == 0) *flag = 0;
    __syncthreads();
    if (tid < 128) {
        if (K_hist[s * 3] != 0.0f || K_hist[s * 3 + 1] != 0.0f || K_hist[s * 3 + 2] != 0.0f)
            atomicOr(flag, 1);
    }
}

// ---------------------------------------------------------------------------
// K2 (production): dual GEMM, 1250 blocks x 16t, thread 2t x 4s, LDS-staged.
// MEASURED ~19.7 µs (R8/R9/R10 algebra) — best of {32t LDS 28.3, LDS-free 48}.
// ---------------------------------------------------------------------------
__global__ void __launch_bounds__(256) k2_gemm16(const float* __restrict__ Z,
                                                 const float* __restrict__ Y,
                                                 const float* __restrict__ Ct,
                                                 float* __restrict__ A,
                                                 float* __restrict__ R) {
    __shared__ float Zt[16 * 128];
    __shared__ float Yt[16 * 128];
    const int t0  = blockIdx.x * 16;
    const int tid = threadIdx.x;
    {
        const float4* Zg = (const float4*)(Z + t0 * S_NO);
        const float4* Yg = (const float4*)(Y + t0 * S_NO);
        float4* Zl = (float4*)Zt;
        float4* Yl = (float4*)Yt;
        for (int q = tid; q < 512; q += 256) { Zl[q] = Zg[q]; Yl[q] = Yg[q]; }
    }
    __syncthreads();
    const int sg = tid & 31;          // s0 = sg*4
    const int tg = tid >> 5;          // 0..7 -> local t = tg*2 + i
    const int s0 = sg * 4;
    float4 accA[2] = {{0,0,0,0},{0,0,0,0}};
    float4 accR[2] = {{0,0,0,0},{0,0,0,0}};
    for (int k4 = 0; k4 < 32; ++k4) {
        const float4 c0 = *(const float4*)&Ct[(k4 * 4 + 0) * S_NO + s0];
        const float4 c1 = *(const float4*)&Ct[(k4 * 4 + 1) * S_NO + s0];
        const float4 c2 = *(const float4*)&Ct[(k4 * 4 + 2) * S_NO + s0];
        const float4 c3 = *(const float4*)&Ct[(k4 * 4 + 3) * S_NO + s0];
#pragma unroll
        for (int i = 0; i < 2; ++i) {
            const float4 z = *(const float4*)&Zt[(tg * 2 + i) * S_NO + k4 * 4];
            fma4(accA[i], z.x, c0); fma4(accA[i], z.y, c1);
            fma4(accA[i], z.z, c2); fma4(accA[i], z.w, c3);
            const float4 y = *(const float4*)&Yt[(tg * 2 + i) * S_NO + k4 * 4];
            fma4(accR[i], y.x, c0); fma4(accR[i], y.y, c1);
            fma4(accR[i], y.z, c2); fma4(accR[i], y.w, c3);
        }
    }
#pragma unroll
    for (int i = 0; i < 2; ++i) {
        *(float4*)&A[(t0 + tg * 2 + i) * S_NO + s0] = accA[i];
        *(float4*)&R[(t0 + tg * 2 + i) * S_NO + s0] = accR[i];
    }
}

// ---------------------------------------------------------------------------
// K3: fused 100-tap conv + final map — EXACT R7 version (measured ~22 µs):
// thread = one s, 8 t's; 13 chunks of 8 taps; double-buffered chunk pipeline;
// prefetched cold streams; bijective XCD swizzle over 1256 = 8*157 blocks.
// ---------------------------------------------------------------------------
#define K3_LOGICAL 1250
#define K3_NPER    157                 // ceil(1250/8)
#define K3_PHYS    (8 * K3_NPER)       // 1256

__device__ __forceinline__ void k3_load_chunk(const float* __restrict__ A,
                                              const float* __restrict__ kT,
                                              int t0, int s, int c,
                                              float w[15], float kj[8]) {
    const int B = t0 - 8 * c - 8;
#pragma unroll
    for (int q = 0; q < 15; ++q) w[q] = A[(B + q) * S_NO + s];
#pragma unroll
    for (int r = 0; r < 8; ++r) kj[r] = kT[(8 * c + r) * S_NO + s];
}

__device__ __forceinline__ void k3_fma_chunk(const float w[15], const float kj[8],
                                             float acc[8]) {
#pragma unroll
    for (int r = 0; r < 8; ++r)
#pragma unroll
        for (int i = 0; i < 8; ++i)
            acc[i] = fmaf(kj[r], w[i + 7 - r], acc[i]);   // row = t0+i-1-(8c+r)
}

__device__ __forceinline__ void conv8_guard(const float* __restrict__ A,
                                            const float* __restrict__ kT,
                                            int t0, int s, float acc[8]) {
#pragma unroll 1
    for (int c = 0; c < 13; ++c) {
        const int B = t0 - 8 * c - 8;
        float w[15], kj[8];
#pragma unroll
        for (int q = 0; q < 15; ++q) {
            const int u = B + q;
            w[q] = (u >= 0) ? A[u * S_NO + s] : 0.0f;
        }
#pragma unroll
        for (int r = 0; r < 8; ++r) kj[r] = kT[(8 * c + r) * S_NO + s];
        k3_fma_chunk(w, kj, acc);
    }
}

__global__ void __launch_bounds__(256, 4) k3_fused(const float* __restrict__ A,
                                                const float* __restrict__ anc_kT,
                                                const float* __restrict__ S_conv,
                                                const float* __restrict__ noise,
                                                const float* __restrict__ W_sub,
                                                const float* __restrict__ theta_syn,
                                                const float* __restrict__ theta_spike,
                                                const float* __restrict__ W_spike,
                                                const int* __restrict__ flag,
                                                float* __restrict__ out0,
                                                float* __restrict__ out1,
                                                float* __restrict__ out2,
                                                float* __restrict__ out3,
                                                float* __restrict__ Fws) {
    const int blk = (blockIdx.x & 7) * K3_NPER + (blockIdx.x >> 3);
    if (blk >= K3_LOGICAL) return;
    const int tid = threadIdx.x;
    const int s   = tid & 127;
    const int tg  = tid >> 7;                             // wave-uniform (0/1)
    const int t0  = blk * 16 + tg * 8;
    const int fl  = *flag;

    float sc[8], nz[8];
#pragma unroll
    for (int i = 0; i < 8; ++i) {
        const int n = (t0 + i) * S_NO + s;
        sc[i] = S_conv[n];
        nz[i] = noise[n];
    }

    float acc[8] = {0,0,0,0,0,0,0,0};
    if (t0 >= J_PAD) {
        float w0[15], k0[8], w1[15], k1[8];
        k3_load_chunk(A, anc_kT, t0, s, 0, w0, k0);
#pragma unroll 1
        for (int c = 0; c < 12; c += 2) {
            k3_load_chunk(A, anc_kT, t0, s, c + 1, w1, k1);
            k3_fma_chunk(w0, k0, acc);
            k3_load_chunk(A, anc_kT, t0, s, c + 2, w0, k0);
            k3_fma_chunk(w1, k1, acc);
        }
        k3_fma_chunk(w0, k0, acc);                        // chunk 12
    } else {
        conv8_guard(A, anc_kT, t0, s, acc);
    }

    if (fl == 0) {
        const float tsy = theta_syn[s], wsub = W_sub[s];
        const float wsp = W_spike[s],  tsp  = theta_spike[s];
#pragma unroll
        for (int i = 0; i < 8; ++i) {
            const int n = (t0 + i) * S_NO + s;
            const float x  = sigm(sc[i] + tsy + out1[n] + acc[i]);
            const float dn = fmaf(x, wsp, tsp);
            const float z  = sigm(dn + nz[i]);
            out0[n] = x * wsub;
            out1[n] = z;
            out2[n] = dn;
            out3[n] = dn;
        }
    } else {
#pragma unroll
        for (int i = 0; i < 8; ++i) Fws[(t0 + i) * S_NO + s] = acc[i];
    }
}

// ---------------------------------------------------------------------------
// K4: exact sequential recurrence (only when hist kernel != 0).
// ---------------------------------------------------------------------------
__global__ void __launch_bounds__(64) k4_scan(const float* __restrict__ S_conv,
                                              const float* __restrict__ noise,
                                              const float* __restrict__ W_sub,
                                              const float* __restrict__ theta_syn,
                                              const float* __restrict__ theta_spike,
                                              const float* __restrict__ W_spike,
                                              const float* __restrict__ hist_k,
                                              const int* __restrict__ flag,
                                              const float* __restrict__ Fws,
                                              float* __restrict__ out0,
                                              float* __restrict__ out1,
                                              float* __restrict__ out2,
                                              float* __restrict__ out3) {
    if (*flag == 0) return;
    __shared__ float zr[128];
    const int s = blockIdx.x;
    const int l = threadIdx.x;
    zr[l] = 0.0f; zr[l + 64] = 0.0f;
    const float hk0 = (l < T_HIST) ? hist_k[s * T_HIST + l] : 0.0f;
    const float hk1 = (l + 64 < T_HIST) ? hist_k[s * T_HIST + l + 64] : 0.0f;
    const float tsy = theta_syn[s], wsub = W_sub[s];
    const float wsp = W_spike[s],  tsp  = theta_spike[s];
    for (int t = 0; t < T_DATA; ++t) {
        float fh = hk0 * zr[(t - 1 - l) & 127];
        fh = fmaf(hk1, zr[(t - 65 - l) & 127], fh);
#pragma unroll
        for (int m = 1; m < 64; m <<= 1) fh += __shfl_xor(fh, m, 64);
        const int n = t * S_NO + s;
        const float basev = S_conv[n] + tsy + out1[n] + Fws[n];
        const float x  = sigm(basev + fh);
        const float dn = fmaf(x, wsp, tsp);
        const float z  = sigm(dn + noise[n]);
        if (l == 0) {
            out0[n] = x * wsub;
            out1[n] = z;
            out2[n] = dn;
            out3[n] = dn;
            zr[t & 127] = z;
        }
    }
}

// ---------------------------------------------------------------------------
extern "C" void kernel_launch(void* const* d_in, const int* in_sizes, int n_in,
                              void* d_out, int out_size, void* d_ws, size_t ws_size,
                              hipStream_t stream) {
    const float* S_conv  = (const float*)d_in[0];
    const float* Y_anc   = (const float*)d_in[1];
    const float* Z_anc   = (const float*)d_in[2];
    const float* noise   = (const float*)d_in[3];
    const float* C_den   = (const float*)d_in[4];
    const float* W_sub   = (const float*)d_in[5];
    const float* th_syn  = (const float*)d_in[6];
    const float* K_spk   = (const float*)d_in[7];
    const float* tau_spk = (const float*)d_in[8];
    const float* dl_spk  = (const float*)d_in[9];
    const float* th_spk  = (const float*)d_in[10];
    const float* W_spk   = (const float*)d_in[11];
    const float* tau_h   = (const float*)d_in[12];
    const float* K_h     = (const float*)d_in[13];
    const float* dl_h    = (const float*)d_in[14];

    float* out  = (float*)d_out;
    float* out0 = out;
    float* out1 = out + NELEM;
    float* out2 = out + 2 * NELEM;
    float* out3 = out + 3 * NELEM;

    // workspace: A | F | Ct | anc_kT (104 rows) | hist_k | flag
    float* ws     = (float*)d_ws;
    float* wsA    = ws;
    float* wsF    = ws + NELEM;
    float* Ct     = ws + 2 * NELEM;
    float* anc_kT = Ct + S_NO * S_NO;
    float* hist_k = anc_kT + J_PAD * S_NO;
    int*   flag   = (int*)(hist_k + S_NO * T_HIST);

    k1_prep<<<17, 256, 0, stream>>>(C_den, K_spk, tau_spk, dl_spk, tau_h, K_h, dl_h,
                                    Ct, anc_kT, hist_k, flag);
    // A -> ws, R -> out1
    k2_gemm16<<<T_DATA / 16, 256, 0, stream>>>(Z_anc, Y_anc, Ct, wsA, out1);
    // fused conv + final map (reads A from ws, R from out1)
    k3_fused<<<K3_PHYS, 256, 0, stream>>>(wsA, anc_kT, S_conv, noise,
                                          W_sub, th_syn, th_spk, W_spk,
                                          flag, out0, out1, out2, out3, wsF);
    // exact sequential path (no-op when hist kernel is all-zero)
    k4_scan<<<S_NO, 64, 0, stream>>>(S_conv, noise, W_sub, th_syn, th_spk, W_spk,
                                     hist_k, flag, wsF, out0, out1, out2, out3);
}